// Round 11
// baseline (529.392 us; speedup 1.0000x reference)
//
#include <hip/hip_runtime.h>

#define N_NODES 50000

typedef __bf16 bf16x8 __attribute__((ext_vector_type(8)));
typedef float f32x4 __attribute__((ext_vector_type(4)));

union U16x8 { uint4 v; unsigned short u[8]; bf16x8 b; };

__device__ __forceinline__ float b2f(unsigned short h){
  unsigned int u = ((unsigned int)h) << 16;
  return __builtin_bit_cast(float, u);
}
__device__ __forceinline__ unsigned short f2b(float x){
  unsigned int u = __builtin_bit_cast(unsigned int, x);
  u = u + 0x7FFFu + ((u >> 16) & 1u);
  return (unsigned short)(u >> 16);
}
// raw-hardware sigmoid/tanh: v_exp_f32 + v_rcp_f32, no division refinement.
__device__ __forceinline__ float sigm(float x){
  const float e = __builtin_amdgcn_exp2f(x * -1.4426950408889634f);
  return __builtin_amdgcn_rcpf(1.0f + e);
}
__device__ __forceinline__ float tanh_(float x){
  const float e = __builtin_amdgcn_exp2f(x * 2.8853900817779268f);
  return fmaf(-2.0f, __builtin_amdgcn_rcpf(1.0f + e), 1.0f);
}

// 8 consecutive f32 -> bf16x8 (RNE), hi only
__device__ __forceinline__ bf16x8 load8_bf16(const float* p){
  float4 a = *(const float4*)p; float4 c = *(const float4*)(p + 4);
  U16x8 r;
  r.u[0]=f2b(a.x); r.u[1]=f2b(a.y); r.u[2]=f2b(a.z); r.u[3]=f2b(a.w);
  r.u[4]=f2b(c.x); r.u[5]=f2b(c.y); r.u[6]=f2b(c.z); r.u[7]=f2b(c.w);
  return r.b;
}

// ---------------------------------------------------------------------------
// Activation tables (all inter-layer tensors): u16[node][64], bf16 hi of fp32.
// ---------------------------------------------------------------------------

// ---------------------------------------------------------------------------
// Layer 1 (d=11) via MFMA, bf16 hi-only, single barrier per step.
// ---------------------------------------------------------------------------
__global__ __launch_bounds__(256) void l1_kernel(
    const float* __restrict__ x, const int* __restrict__ nbr,
    const float* __restrict__ Wih, const float* __restrict__ Whh,
    const float* __restrict__ bih, const float* __restrict__ bhh,
    const float* __restrict__ Ws,  const float* __restrict__ bs,
    const float* __restrict__ Wn,  unsigned short* __restrict__ out_hl)
{
  __shared__ unsigned short mbuf[16][16][24];  // [t][node][k] 12.3 KB
  __shared__ unsigned short hbuf[2][16][24];   // [buf][node][unit] 1.5 KB

  const int tid  = threadIdx.x;
  const int wave = tid >> 6, lane = tid & 63;
  const int n16  = lane & 15, q = lane >> 4;
  const int nb0  = blockIdx.x * 16;

  { unsigned int* p = (unsigned int*)hbuf;
    for (int i = tid; i < 384; i += 256) p[i] = 0u; }

  {
    const int nd = tid >> 4, t = tid & 15;
    const int gn = nbr[(nb0 + nd) * 16 + t];
    const float* row = x + (long)gn * 11;
    float v[16];
    #pragma unroll
    for (int j = 0; j < 11; j++) v[j] = row[j];
    #pragma unroll
    for (int j = 11; j < 16; j++) v[j] = 0.f;
    U16x8 A, B;
    #pragma unroll
    for (int j = 0; j < 8; j++){ A.u[j] = f2b(v[j]); B.u[j] = f2b(v[8 + j]); }
    *(uint4*)&mbuf[t][nd][0] = A.v;
    *(uint4*)&mbuf[t][nd][8] = B.v;
  }

  bf16x8 wf[4];
  float bg4[4];
  #pragma unroll
  for (int g = 0; g < 4; g++){
    const int u = n16;
    const float* src = (q < 2) ? (Wih + (g * 11 + u) * 11)
                               : (Whh + (g * 11 + u) * 11);
    const int kb = (q & 1) * 8;
    U16x8 a;
    #pragma unroll
    for (int j = 0; j < 8; j++){
      const int k = kb + j;
      float v = (u < 11 && k < 11) ? src[k] : 0.f;
      a.u[j] = f2b(v);
    }
    wf[g] = a.b;
    bg4[g] = (n16 < 11) ? (bih[g * 11 + n16] + bhh[g * 11 + n16]) : 0.f;
  }

  float c_ = 0.f;   // cell state for (node q*4+wave, unit n16)
  __syncthreads();

  for (int t = 0; t < 16; t++){
    const int db = t & 1, nb = db ^ 1;

    const unsigned short* ph = (q < 2) ? &mbuf[t][n16][q * 8]
                                       : &hbuf[db][n16][(q - 2) * 8];
    U16x8 ah; ah.v = *(const uint4*)ph;

    f32x4 acc[4];
    #pragma unroll
    for (int g = 0; g < 4; g++){
      f32x4 av = {bg4[g], bg4[g], bg4[g], bg4[g]};
      acc[g] = __builtin_amdgcn_mfma_f32_16x16x32_bf16(ah.b, wf[g], av, 0, 0, 0);
    }

    {
      const float iv = sigm(acc[0][wave]);
      const float fv = sigm(acc[1][wave]);
      const float gg = tanh_(acc[2][wave]);
      const float ov = sigm(acc[3][wave]);
      c_ = fv * c_ + iv * gg;
      hbuf[nb][q * 4 + wave][n16] = f2b(ov * tanh_(c_));
    }
    __syncthreads();
  }

  // ---- epilogue ----
  U16x8 ea;
  if (q < 2){
    const float* row = x + (long)(nb0 + n16) * 11;
    U16x8 H;
    #pragma unroll
    for (int j = 0; j < 8; j++){
      const int k = q * 8 + j;
      H.u[j] = f2b((k < 11) ? row[k] : 0.f);
    }
    ea = H;
  } else {
    ea.v = *(const uint4*)&hbuf[0][n16][(q - 2) * 8];
  }

  bf16x8 ewf;
  {
    const int uo = wave * 16 + n16;
    const float* src = (q < 2) ? (Ws + uo * 11) : (Wn + uo * 11);
    const int kb = (q & 1) * 8;
    U16x8 a;
    #pragma unroll
    for (int j = 0; j < 8; j++){
      const int k = kb + j;
      a.u[j] = f2b((k < 11) ? src[k] : 0.f);
    }
    ewf = a.b;
  }

  {
    const int uo = wave * 16 + n16;
    const float bsv = bs[uo];
    f32x4 e = {bsv, bsv, bsv, bsv};
    e = __builtin_amdgcn_mfma_f32_16x16x32_bf16(ea.b, ewf, e, 0, 0, 0);
    #pragma unroll
    for (int r = 0; r < 4; r++)
      out_hl[(size_t)(nb0 + q * 4 + r) * 64 + uo] = f2b(fmaxf(e[r], 0.f));
  }
}

// ---------------------------------------------------------------------------
// Layers 2/3/4: transposed MFMA (A=weights rows=units, B=[m;h] cols=nodes),
// bf16 hi-only activations. ROLLING GATHER PIPELINE: 4-slot mbuf ring;
// step t consumes row-set t, LDS-stores row-set t+2 (held in 1 uint2/thread
// since step t-1), issues global load for row-set t+3. Fetch is spread over
// 13 steps (no startup burst; latency covered by a full step). LDS 13.3 KB.
// __launch_bounds__(256,3) ONLY: (256,4) forced VGPR=64 (spill, 137 MB
// WRITE), (256,5) forced VGPR=48 (spill, 293 MB WRITE). 3 -> ~84 VGPR clean.
// mode 0: out_hl = relu(hself@WsT + bs + hK@WnT)          (u16 table)
// mode 1: out_f32[n] = hself@WsT + bs + hK@WnT (o=1)
// mode 2: mode-0 compute (=h3, NOT stored globally) + fused GRUCell:
//         out_hl = (1-z)*n + z*prev  with x=h3 staged via hbuf[1]
// ---------------------------------------------------------------------------
__global__ __launch_bounds__(256, 3) void sage64_kernel(
    const unsigned short* __restrict__ in_hl, const int* __restrict__ nbr,
    const float* __restrict__ Wih, const float* __restrict__ Whh,
    const float* __restrict__ bih, const float* __restrict__ bhh,
    const float* __restrict__ Ws,  const float* __restrict__ bs,
    const float* __restrict__ Wn,
    const float* __restrict__ gWih, const float* __restrict__ gWhh,
    const float* __restrict__ gbih, const float* __restrict__ gbhh,
    const float* __restrict__ prevp,
    unsigned short* __restrict__ out_hl, float* __restrict__ out_f32, int mode)
{
  __shared__ uint4 mbuf[4][16][8];    // ring [t&3][node][slot sw (s+nd+t)&7] 8 KB
  __shared__ uint4 hbuf[2][16][8];    // [buf][node][slot sw (s+n)&7]         4 KB
  __shared__ int nbr_s[16 * 17];      // padded neighbor ids                 1.1 KB

  const int tid = threadIdx.x;
  const int wv = tid >> 6, lane = tid & 63;
  const int n16 = lane & 15, q = lane >> 4;
  const int nb0 = blockIdx.x * 16;
  const int nd = tid >> 4, part = tid & 15;      // gather role: node nd, 8B part
  const int sl = part >> 1, hf = part & 1;       // 16B slot + uint2 half

  // stage neighbor ids (row-major, padded stride 17)
  nbr_s[nd * 17 + part] = nbr[(nb0 + nd) * 16 + part];

  // prologue: load + store row-sets 0,1,2 (thread = 8B of node nd's row)
  {
    const int gn0 = nbr[(nb0 + nd) * 16 + 0];
    const int gn1 = nbr[(nb0 + nd) * 16 + 1];
    const int gn2 = nbr[(nb0 + nd) * 16 + 2];
    uint2 g0 = *(const uint2*)(in_hl + (size_t)gn0 * 64 + part * 4);
    uint2 g1 = *(const uint2*)(in_hl + (size_t)gn1 * 64 + part * 4);
    uint2 g2 = *(const uint2*)(in_hl + (size_t)gn2 * 64 + part * 4);
    ((uint2*)&mbuf[0][nd][(sl + nd + 0) & 7])[hf] = g0;
    ((uint2*)&mbuf[1][nd][(sl + nd + 1) & 7])[hf] = g1;
    ((uint2*)&mbuf[2][nd][(sl + nd + 2) & 7])[hf] = g2;
  }
  // zero hbuf[0] (initial h)
  { unsigned int* p = (unsigned int*)&hbuf[0][0][0];
    for (int i = tid; i < 512; i += 256) p[i] = 0u; }

  // resident weight A-frags (hi only): gate g, kc; lane row = unit wv*16+n16
  bf16x8 wih_f[4][2], whh_f[4][2];
  #pragma unroll
  for (int g = 0; g < 4; g++){
    const int row = g * 64 + wv * 16 + n16;
    #pragma unroll
    for (int kc = 0; kc < 2; kc++){
      wih_f[g][kc] = load8_bf16(Wih + row * 64 + kc * 32 + q * 8);
      whh_f[g][kc] = load8_bf16(Whh + row * 64 + kc * 32 + q * 8);
    }
  }
  f32x4 bg[4];
  #pragma unroll
  for (int g = 0; g < 4; g++){
    float4 bi = *(const float4*)(bih + g * 64 + wv * 16 + q * 4);
    float4 bh = *(const float4*)(bhh + g * 64 + wv * 16 + q * 4);
    f32x4 s = {bi.x + bh.x, bi.y + bh.y, bi.z + bh.z, bi.w + bh.w};
    bg[g] = s;
  }

  float c4[4] = {0.f, 0.f, 0.f, 0.f};
  uint2 gv = make_uint2(0u, 0u);       // in-flight gather (row-set t+3)
  __syncthreads();

  for (int t = 0; t < 16; t++){
    const int db = t & 1, nbf = db ^ 1;

    // phase 1: consume row-set t (and h_t)
    bf16x8 mh[2], hh[2];
    #pragma unroll
    for (int kc = 0; kc < 2; kc++){
      U16x8 a; a.v = mbuf[t & 3][n16][(kc * 4 + q + n16 + t) & 7]; mh[kc] = a.b;
      U16x8 c_; c_.v = hbuf[db][n16][(kc * 4 + q + n16) & 7];      hh[kc] = c_.b;
    }

    // phase 2: store row-set t+2 (loaded during step t-1) into the ring
    if (t >= 1 && t <= 13){
      const int rs = t + 2;
      ((uint2*)&mbuf[rs & 3][nd][(sl + nd + rs) & 7])[hf] = gv;
    }
    // phase 3: issue load for row-set t+3 (consumed 3 steps later)
    if (t <= 12){
      const int rs = t + 3;
      const int gn = nbr_s[nd * 17 + rs];
      gv = *(const uint2*)(in_hl + (size_t)gn * 64 + part * 4);
    }

    f32x4 acc[4];
    #pragma unroll
    for (int g = 0; g < 4; g++) acc[g] = bg[g];
    #pragma unroll
    for (int kc = 0; kc < 2; kc++){
      #pragma unroll
      for (int g = 0; g < 4; g++)
        acc[g] = __builtin_amdgcn_mfma_f32_16x16x32_bf16(wih_f[g][kc], mh[kc], acc[g], 0, 0, 0);
      #pragma unroll
      for (int g = 0; g < 4; g++)
        acc[g] = __builtin_amdgcn_mfma_f32_16x16x32_bf16(whh_f[g][kc], hh[kc], acc[g], 0, 0, 0);
    }

    unsigned short hB[4];
    #pragma unroll
    for (int r = 0; r < 4; r++){
      const float iv = sigm(acc[0][r]);
      const float fv = sigm(acc[1][r]);
      const float gg = tanh_(acc[2][r]);
      const float ov = sigm(acc[3][r]);
      c4[r] = fv * c4[r] + iv * gg;
      hB[r] = f2b(ov * tanh_(c4[r]));
    }
    {
      const int idx = wv * 4 + q;            // uint2 index within node row
      const int slot = idx >> 1, half = idx & 1;
      ((uint2*)&hbuf[nbf][n16][(slot + n16) & 7])[half] =
          make_uint2((unsigned)hB[0] | ((unsigned)hB[1] << 16),
                     (unsigned)hB[2] | ((unsigned)hB[3] << 16));
    }
    __syncthreads();
  }

  // ---- epilogue: B = hself (global, hi) and hK (hbuf[0]) ----
  bf16x8 sH[2], kH[2];
  #pragma unroll
  for (int kc = 0; kc < 2; kc++){
    U16x8 a; a.v = *(const uint4*)(in_hl + (size_t)(nb0 + n16) * 64 + kc * 32 + q * 8);
    sH[kc] = a.b;
    U16x8 c_; c_.v = hbuf[0][n16][(kc * 4 + q + n16) & 7]; kH[kc] = c_.b;
  }

  if (mode != 1){
    bf16x8 ws_f[2], wn_f[2];
    #pragma unroll
    for (int kc = 0; kc < 2; kc++){
      ws_f[kc] = load8_bf16(Ws + (wv * 16 + n16) * 64 + kc * 32 + q * 8);
      wn_f[kc] = load8_bf16(Wn + (wv * 16 + n16) * 64 + kc * 32 + q * 8);
    }
    float4 bsv = *(const float4*)(bs + wv * 16 + q * 4);
    f32x4 e = {bsv.x, bsv.y, bsv.z, bsv.w};
    #pragma unroll
    for (int kc = 0; kc < 2; kc++){
      e = __builtin_amdgcn_mfma_f32_16x16x32_bf16(ws_f[kc], sH[kc], e, 0, 0, 0);
      e = __builtin_amdgcn_mfma_f32_16x16x32_bf16(wn_f[kc], kH[kc], e, 0, 0, 0);
    }
    unsigned short oB[4];
    #pragma unroll
    for (int r = 0; r < 4; r++) oB[r] = f2b(fmaxf(e[r], 0.f));
    const uint2 packed = make_uint2((unsigned)oB[0] | ((unsigned)oB[1] << 16),
                                    (unsigned)oB[2] | ((unsigned)oB[3] << 16));

    if (mode == 0){
      *(uint2*)(out_hl + (size_t)(nb0 + n16) * 64 + wv * 16 + q * 4) = packed;
    } else {
      // ---- mode 2: fused GRUCell. Stage h3 into hbuf[1] (B-frag layout) ----
      {
        const int idx = wv * 4 + q;
        const int slot = idx >> 1, half = idx & 1;
        ((uint2*)&hbuf[1][n16][(slot + n16) & 7])[half] = packed;
      }
      __syncthreads();

      // B-frags: x3 = h3 (from hbuf[1]), pv = prev (global fp32 -> bf16)
      bf16x8 x3[2], pv[2];
      #pragma unroll
      for (int kc = 0; kc < 2; kc++){
        U16x8 a; a.v = hbuf[1][n16][(kc * 4 + q + n16) & 7]; x3[kc] = a.b;
        pv[kc] = load8_bf16(prevp + (size_t)(nb0 + n16) * 64 + kc * 32 + q * 8);
      }
      // gru weight A-frags (3 gates r,z,n)
      bf16x8 wi_f[3][2], wh_f[3][2];
      #pragma unroll
      for (int g = 0; g < 3; g++){
        const int row = g * 64 + wv * 16 + n16;
        #pragma unroll
        for (int kc = 0; kc < 2; kc++){
          wi_f[g][kc] = load8_bf16(gWih + row * 64 + kc * 32 + q * 8);
          wh_f[g][kc] = load8_bf16(gWhh + row * 64 + kc * 32 + q * 8);
        }
      }
      f32x4 gi[3], gh[3];
      #pragma unroll
      for (int g = 0; g < 3; g++){
        float4 bi = *(const float4*)(gbih + g * 64 + wv * 16 + q * 4);
        float4 bh = *(const float4*)(gbhh + g * 64 + wv * 16 + q * 4);
        f32x4 vi = {bi.x, bi.y, bi.z, bi.w}; gi[g] = vi;
        f32x4 vh = {bh.x, bh.y, bh.z, bh.w}; gh[g] = vh;
      }
      #pragma unroll
      for (int kc = 0; kc < 2; kc++){
        #pragma unroll
        for (int g = 0; g < 3; g++)
          gi[g] = __builtin_amdgcn_mfma_f32_16x16x32_bf16(wi_f[g][kc], x3[kc], gi[g], 0, 0, 0);
        #pragma unroll
        for (int g = 0; g < 3; g++)
          gh[g] = __builtin_amdgcn_mfma_f32_16x16x32_bf16(wh_f[g][kc], pv[kc], gh[g], 0, 0, 0);
      }
      // gates: lane (n16=node, q) holds units wv*16+q*4+r
      float4 hp4 = *(const float4*)(prevp + (size_t)(nb0 + n16) * 64 + wv * 16 + q * 4);
      const float hp[4] = {hp4.x, hp4.y, hp4.z, hp4.w};
      unsigned short gB[4];
      #pragma unroll
      for (int r = 0; r < 4; r++){
        const float rv = sigm(gi[0][r] + gh[0][r]);
        const float zv = sigm(gi[1][r] + gh[1][r]);
        const float nv = tanh_(gi[2][r] + rv * gh[2][r]);
        gB[r] = f2b((1.f - zv) * nv + zv * hp[r]);
      }
      *(uint2*)(out_hl + (size_t)(nb0 + n16) * 64 + wv * 16 + q * 4) =
          make_uint2((unsigned)gB[0] | ((unsigned)gB[1] << 16),
                     (unsigned)gB[2] | ((unsigned)gB[3] << 16));
    }
  } else {
    // mode 1: o=1 logits
    if (wv == 0){
      bf16x8 ws_f[2], wn_f[2];
      #pragma unroll
      for (int kc = 0; kc < 2; kc++){
        U16x8 a, b_;
        a.v = make_uint4(0u,0u,0u,0u); b_.v = make_uint4(0u,0u,0u,0u);
        if (n16 == 0){
          a.b  = load8_bf16(Ws + kc * 32 + q * 8);
          b_.b = load8_bf16(Wn + kc * 32 + q * 8);
        }
        ws_f[kc] = a.b; wn_f[kc] = b_.b;
      }
      f32x4 e = {0.f, 0.f, 0.f, 0.f};
      #pragma unroll
      for (int kc = 0; kc < 2; kc++){
        e = __builtin_amdgcn_mfma_f32_16x16x32_bf16(ws_f[kc], sH[kc], e, 0, 0, 0);
        e = __builtin_amdgcn_mfma_f32_16x16x32_bf16(wn_f[kc], kH[kc], e, 0, 0, 0);
      }
      if (q == 0) out_f32[nb0 + n16] = e[0] + bs[0];
    }
  }
}

// ---------------------------------------------------------------------------
extern "C" void kernel_launch(void* const* d_in, const int* in_sizes, int n_in,
                              void* d_out, int out_size, void* d_ws, size_t ws_size,
                              hipStream_t stream)
{
  (void)in_sizes; (void)n_in; (void)out_size; (void)ws_size;
  const float* x    = (const float*)d_in[0];
  const int*   nbr  = (const int*)d_in[1];
  const float* prev = (const float*)d_in[2];
  auto W = [&](int i){ return (const float*)d_in[i]; };

  unsigned short* tabA = (unsigned short*)d_ws;            // [N][64] u16, 6.4 MB
  unsigned short* tabB = tabA + (size_t)N_NODES * 64;      // second table

  // layer 1 (d=11): x -> tabA (=h1)
  l1_kernel<<<N_NODES / 16, 256, 0, stream>>>(
      x, nbr, W(3), W(4), W(5), W(6), W(7), W(8), W(9), tabA);
  // layer 2: tabA -> tabB (=h2)
  sage64_kernel<<<N_NODES / 16, 256, 0, stream>>>(
      tabA, nbr, W(10), W(11), W(12), W(13), W(14), W(15), W(16),
      nullptr, nullptr, nullptr, nullptr, nullptr,
      tabB, nullptr, 0);
  // layer 3 + fused GRU: tabB (+prev) -> tabA (= GRU output h)
  sage64_kernel<<<N_NODES / 16, 256, 0, stream>>>(
      tabB, nbr, W(17), W(18), W(19), W(20), W(21), W(22), W(23),
      W(31), W(32), W(33), W(34), prev,
      tabA, nullptr, 2);
  // layer 4 (o=1): tabA -> d_out (fp32 logits)
  sage64_kernel<<<N_NODES / 16, 256, 0, stream>>>(
      tabA, nbr, W(24), W(25), W(26), W(27), W(28), W(29), W(30),
      nullptr, nullptr, nullptr, nullptr, nullptr,
      nullptr, (float*)d_out, 1);
}

// Round 12
// 481.070 us; speedup vs baseline: 1.1004x; 1.1004x over previous
//
#include <hip/hip_runtime.h>

#define N_NODES 50000

typedef __bf16 bf16x8 __attribute__((ext_vector_type(8)));
typedef float f32x4 __attribute__((ext_vector_type(4)));

union U16x8 { uint4 v; unsigned short u[8]; bf16x8 b; };

__device__ __forceinline__ float b2f(unsigned short h){
  unsigned int u = ((unsigned int)h) << 16;
  return __builtin_bit_cast(float, u);
}
__device__ __forceinline__ unsigned short f2b(float x){
  unsigned int u = __builtin_bit_cast(unsigned int, x);
  u = u + 0x7FFFu + ((u >> 16) & 1u);
  return (unsigned short)(u >> 16);
}
// raw-hardware sigmoid/tanh: v_exp_f32 + v_rcp_f32, no division refinement.
__device__ __forceinline__ float sigm(float x){
  const float e = __builtin_amdgcn_exp2f(x * -1.4426950408889634f);
  return __builtin_amdgcn_rcpf(1.0f + e);
}
__device__ __forceinline__ float tanh_(float x){
  const float e = __builtin_amdgcn_exp2f(x * 2.8853900817779268f);
  return fmaf(-2.0f, __builtin_amdgcn_rcpf(1.0f + e), 1.0f);
}

// 8 consecutive f32 -> bf16x8 (RNE), hi only
__device__ __forceinline__ bf16x8 load8_bf16(const float* p){
  float4 a = *(const float4*)p; float4 c = *(const float4*)(p + 4);
  U16x8 r;
  r.u[0]=f2b(a.x); r.u[1]=f2b(a.y); r.u[2]=f2b(a.z); r.u[3]=f2b(a.w);
  r.u[4]=f2b(c.x); r.u[5]=f2b(c.y); r.u[6]=f2b(c.z); r.u[7]=f2b(c.w);
  return r.b;
}

// ---------------------------------------------------------------------------
// Activation tables (all inter-layer tensors): u16[node][64], bf16 hi of fp32.
// ---------------------------------------------------------------------------

// ---------------------------------------------------------------------------
// Layer 1 (d=11) via MFMA, bf16 hi-only, single barrier per step. (~20 us)
// ---------------------------------------------------------------------------
__global__ __launch_bounds__(256) void l1_kernel(
    const float* __restrict__ x, const int* __restrict__ nbr,
    const float* __restrict__ Wih, const float* __restrict__ Whh,
    const float* __restrict__ bih, const float* __restrict__ bhh,
    const float* __restrict__ Ws,  const float* __restrict__ bs,
    const float* __restrict__ Wn,  unsigned short* __restrict__ out_hl)
{
  __shared__ unsigned short mbuf[16][16][24];  // [t][node][k] 12.3 KB
  __shared__ unsigned short hbuf[2][16][24];   // [buf][node][unit] 1.5 KB

  const int tid  = threadIdx.x;
  const int wave = tid >> 6, lane = tid & 63;
  const int n16  = lane & 15, q = lane >> 4;
  const int nb0  = blockIdx.x * 16;

  { unsigned int* p = (unsigned int*)hbuf;
    for (int i = tid; i < 384; i += 256) p[i] = 0u; }

  {
    const int nd = tid >> 4, t = tid & 15;
    const int gn = nbr[(nb0 + nd) * 16 + t];
    const float* row = x + (long)gn * 11;
    float v[16];
    #pragma unroll
    for (int j = 0; j < 11; j++) v[j] = row[j];
    #pragma unroll
    for (int j = 11; j < 16; j++) v[j] = 0.f;
    U16x8 A, B;
    #pragma unroll
    for (int j = 0; j < 8; j++){ A.u[j] = f2b(v[j]); B.u[j] = f2b(v[8 + j]); }
    *(uint4*)&mbuf[t][nd][0] = A.v;
    *(uint4*)&mbuf[t][nd][8] = B.v;
  }

  bf16x8 wf[4];
  float bg4[4];
  #pragma unroll
  for (int g = 0; g < 4; g++){
    const int u = n16;
    const float* src = (q < 2) ? (Wih + (g * 11 + u) * 11)
                               : (Whh + (g * 11 + u) * 11);
    const int kb = (q & 1) * 8;
    U16x8 a;
    #pragma unroll
    for (int j = 0; j < 8; j++){
      const int k = kb + j;
      float v = (u < 11 && k < 11) ? src[k] : 0.f;
      a.u[j] = f2b(v);
    }
    wf[g] = a.b;
    bg4[g] = (n16 < 11) ? (bih[g * 11 + n16] + bhh[g * 11 + n16]) : 0.f;
  }

  float c_ = 0.f;   // cell state for (node q*4+wave, unit n16)
  __syncthreads();

  for (int t = 0; t < 16; t++){
    const int db = t & 1, nb = db ^ 1;

    const unsigned short* ph = (q < 2) ? &mbuf[t][n16][q * 8]
                                       : &hbuf[db][n16][(q - 2) * 8];
    U16x8 ah; ah.v = *(const uint4*)ph;

    f32x4 acc[4];
    #pragma unroll
    for (int g = 0; g < 4; g++){
      f32x4 av = {bg4[g], bg4[g], bg4[g], bg4[g]};
      acc[g] = __builtin_amdgcn_mfma_f32_16x16x32_bf16(ah.b, wf[g], av, 0, 0, 0);
    }

    {
      const float iv = sigm(acc[0][wave]);
      const float fv = sigm(acc[1][wave]);
      const float gg = tanh_(acc[2][wave]);
      const float ov = sigm(acc[3][wave]);
      c_ = fv * c_ + iv * gg;
      hbuf[nb][q * 4 + wave][n16] = f2b(ov * tanh_(c_));
    }
    __syncthreads();
  }

  // ---- epilogue ----
  U16x8 ea;
  if (q < 2){
    const float* row = x + (long)(nb0 + n16) * 11;
    U16x8 H;
    #pragma unroll
    for (int j = 0; j < 8; j++){
      const int k = q * 8 + j;
      H.u[j] = f2b((k < 11) ? row[k] : 0.f);
    }
    ea = H;
  } else {
    ea.v = *(const uint4*)&hbuf[0][n16][(q - 2) * 8];
  }

  bf16x8 ewf;
  {
    const int uo = wave * 16 + n16;
    const float* src = (q < 2) ? (Ws + uo * 11) : (Wn + uo * 11);
    const int kb = (q & 1) * 8;
    U16x8 a;
    #pragma unroll
    for (int j = 0; j < 8; j++){
      const int k = kb + j;
      a.u[j] = f2b((k < 11) ? src[k] : 0.f);
    }
    ewf = a.b;
  }

  {
    const int uo = wave * 16 + n16;
    const float bsv = bs[uo];
    f32x4 e = {bsv, bsv, bsv, bsv};
    e = __builtin_amdgcn_mfma_f32_16x16x32_bf16(ea.b, ewf, e, 0, 0, 0);
    #pragma unroll
    for (int r = 0; r < 4; r++)
      out_hl[(size_t)(nb0 + q * 4 + r) * 64 + uo] = f2b(fmaxf(e[r], 0.f));
  }
}

// ---------------------------------------------------------------------------
// Layers 2/3/4: transposed MFMA (A=weights rows=units, B=[m;h] cols=nodes),
// bf16 hi-only activations, ALL 16 m-rows burst-prefetched upfront (r6-proven
// body: 36.9 KB LDS, 117.6 us). Swizzled LDS slots.
// MODE is a TEMPLATE param: r10 proved that compiling the mode-2 GRU epilogue
// into the same function polluted register allocation for ALL modes
// (FETCH 35.6->49.8 MB, dur 117.6->152.9 on pure mode-0 dispatches).
// Separate instantiations give each mode its own clean regalloc.
// __launch_bounds__(256,3) ONLY: (256,4) forced VGPR=64 (spill, 137 MB
// WRITE), (256,5) forced VGPR=48 (spill, 293 MB WRITE). 3 -> 84 VGPR clean.
// MODE 0: out_hl = relu(hself@WsT + bs + hK@WnT)          (u16 table)
// MODE 1: out_f32[n] = hself@WsT + bs + hK@WnT (o=1)
// MODE 2: mode-0 compute (=h3, not stored) + fused GRUCell -> out_hl
//         (fusion kills the standalone gru kernel, ~120 us of dark matter)
// ---------------------------------------------------------------------------
template<int MODE>
__global__ __launch_bounds__(256, 3) void sage64_kernel(
    const unsigned short* __restrict__ in_hl, const int* __restrict__ nbr,
    const float* __restrict__ Wih, const float* __restrict__ Whh,
    const float* __restrict__ bih, const float* __restrict__ bhh,
    const float* __restrict__ Ws,  const float* __restrict__ bs,
    const float* __restrict__ Wn,
    const float* __restrict__ gWih, const float* __restrict__ gWhh,
    const float* __restrict__ gbih, const float* __restrict__ gbhh,
    const float* __restrict__ prevp,
    unsigned short* __restrict__ out_hl, float* __restrict__ out_f32)
{
  __shared__ uint4 mbuf[16][16][8];   // [t][node][slot sw (s+nd+t)&7]  32 KB
  __shared__ uint4 hbuf[2][16][8];    // [buf][node][slot sw (s+n)&7]    4 KB

  const int tid = threadIdx.x;
  const int wv = tid >> 6, lane = tid & 63;
  const int n16 = lane & 15, q = lane >> 4;
  const int nb0 = blockIdx.x * 16;

  // burst prefetch: thread (nd, t) loads one 128B neighbor row
  {
    const int nd = tid >> 4, t = tid & 15;
    const int gn = nbr[(nb0 + nd) * 16 + t];
    const uint4* src = (const uint4*)(in_hl + (size_t)gn * 64);
    #pragma unroll
    for (int s = 0; s < 8; s++)
      mbuf[t][nd][(s + nd + t) & 7] = src[s];
  }
  // zero hbuf[0] (initial h)
  { unsigned int* p = (unsigned int*)&hbuf[0][0][0];
    for (int i = tid; i < 512; i += 256) p[i] = 0u; }

  // resident weight A-frags (hi only): gate g, kc; lane row = unit wv*16+n16
  bf16x8 wih_f[4][2], whh_f[4][2];
  #pragma unroll
  for (int g = 0; g < 4; g++){
    const int row = g * 64 + wv * 16 + n16;
    #pragma unroll
    for (int kc = 0; kc < 2; kc++){
      wih_f[g][kc] = load8_bf16(Wih + row * 64 + kc * 32 + q * 8);
      whh_f[g][kc] = load8_bf16(Whh + row * 64 + kc * 32 + q * 8);
    }
  }
  f32x4 bg[4];
  #pragma unroll
  for (int g = 0; g < 4; g++){
    float4 bi = *(const float4*)(bih + g * 64 + wv * 16 + q * 4);
    float4 bh = *(const float4*)(bhh + g * 64 + wv * 16 + q * 4);
    f32x4 s = {bi.x + bh.x, bi.y + bh.y, bi.z + bh.z, bi.w + bh.w};
    bg[g] = s;
  }

  float c4[4] = {0.f, 0.f, 0.f, 0.f};
  __syncthreads();

  for (int t = 0; t < 16; t++){
    const int db = t & 1, nbf = db ^ 1;

    bf16x8 mh[2], hh[2];
    #pragma unroll
    for (int kc = 0; kc < 2; kc++){
      U16x8 a; a.v = mbuf[t][n16][(kc * 4 + q + n16 + t) & 7];  mh[kc] = a.b;
      U16x8 c_; c_.v = hbuf[db][n16][(kc * 4 + q + n16) & 7];   hh[kc] = c_.b;
    }

    f32x4 acc[4];
    #pragma unroll
    for (int g = 0; g < 4; g++) acc[g] = bg[g];
    #pragma unroll
    for (int kc = 0; kc < 2; kc++){
      #pragma unroll
      for (int g = 0; g < 4; g++)
        acc[g] = __builtin_amdgcn_mfma_f32_16x16x32_bf16(wih_f[g][kc], mh[kc], acc[g], 0, 0, 0);
      #pragma unroll
      for (int g = 0; g < 4; g++)
        acc[g] = __builtin_amdgcn_mfma_f32_16x16x32_bf16(whh_f[g][kc], hh[kc], acc[g], 0, 0, 0);
    }

    unsigned short hB[4];
    #pragma unroll
    for (int r = 0; r < 4; r++){
      const float iv = sigm(acc[0][r]);
      const float fv = sigm(acc[1][r]);
      const float gg = tanh_(acc[2][r]);
      const float ov = sigm(acc[3][r]);
      c4[r] = fv * c4[r] + iv * gg;
      hB[r] = f2b(ov * tanh_(c4[r]));
    }
    {
      const int idx = wv * 4 + q;            // uint2 index within node row
      const int slot = idx >> 1, half = idx & 1;
      ((uint2*)&hbuf[nbf][n16][(slot + n16) & 7])[half] =
          make_uint2((unsigned)hB[0] | ((unsigned)hB[1] << 16),
                     (unsigned)hB[2] | ((unsigned)hB[3] << 16));
    }
    __syncthreads();
  }

  // ---- epilogue: B = hself (global, hi) and hK (hbuf[0]) ----
  bf16x8 sH[2], kH[2];
  #pragma unroll
  for (int kc = 0; kc < 2; kc++){
    U16x8 a; a.v = *(const uint4*)(in_hl + (size_t)(nb0 + n16) * 64 + kc * 32 + q * 8);
    sH[kc] = a.b;
    U16x8 c_; c_.v = hbuf[0][n16][(kc * 4 + q + n16) & 7]; kH[kc] = c_.b;
  }

  if constexpr (MODE != 1){
    bf16x8 ws_f[2], wn_f[2];
    #pragma unroll
    for (int kc = 0; kc < 2; kc++){
      ws_f[kc] = load8_bf16(Ws + (wv * 16 + n16) * 64 + kc * 32 + q * 8);
      wn_f[kc] = load8_bf16(Wn + (wv * 16 + n16) * 64 + kc * 32 + q * 8);
    }
    float4 bsv = *(const float4*)(bs + wv * 16 + q * 4);
    f32x4 e = {bsv.x, bsv.y, bsv.z, bsv.w};
    #pragma unroll
    for (int kc = 0; kc < 2; kc++){
      e = __builtin_amdgcn_mfma_f32_16x16x32_bf16(ws_f[kc], sH[kc], e, 0, 0, 0);
      e = __builtin_amdgcn_mfma_f32_16x16x32_bf16(wn_f[kc], kH[kc], e, 0, 0, 0);
    }
    unsigned short oB[4];
    #pragma unroll
    for (int r = 0; r < 4; r++) oB[r] = f2b(fmaxf(e[r], 0.f));
    const uint2 packed = make_uint2((unsigned)oB[0] | ((unsigned)oB[1] << 16),
                                    (unsigned)oB[2] | ((unsigned)oB[3] << 16));

    if constexpr (MODE == 0){
      *(uint2*)(out_hl + (size_t)(nb0 + n16) * 64 + wv * 16 + q * 4) = packed;
    } else {
      // ---- MODE 2: fused GRUCell. Stage h3 into hbuf[1] (B-frag layout) ----
      {
        const int idx = wv * 4 + q;
        const int slot = idx >> 1, half = idx & 1;
        ((uint2*)&hbuf[1][n16][(slot + n16) & 7])[half] = packed;
      }
      __syncthreads();

      bf16x8 x3[2], pv[2];
      #pragma unroll
      for (int kc = 0; kc < 2; kc++){
        U16x8 a; a.v = hbuf[1][n16][(kc * 4 + q + n16) & 7]; x3[kc] = a.b;
        pv[kc] = load8_bf16(prevp + (size_t)(nb0 + n16) * 64 + kc * 32 + q * 8);
      }
      bf16x8 wi_f[3][2], wh_f[3][2];
      #pragma unroll
      for (int g = 0; g < 3; g++){
        const int row = g * 64 + wv * 16 + n16;
        #pragma unroll
        for (int kc = 0; kc < 2; kc++){
          wi_f[g][kc] = load8_bf16(gWih + row * 64 + kc * 32 + q * 8);
          wh_f[g][kc] = load8_bf16(gWhh + row * 64 + kc * 32 + q * 8);
        }
      }
      f32x4 gi[3], gh[3];
      #pragma unroll
      for (int g = 0; g < 3; g++){
        float4 bi = *(const float4*)(gbih + g * 64 + wv * 16 + q * 4);
        float4 bh = *(const float4*)(gbhh + g * 64 + wv * 16 + q * 4);
        f32x4 vi = {bi.x, bi.y, bi.z, bi.w}; gi[g] = vi;
        f32x4 vh = {bh.x, bh.y, bh.z, bh.w}; gh[g] = vh;
      }
      #pragma unroll
      for (int kc = 0; kc < 2; kc++){
        #pragma unroll
        for (int g = 0; g < 3; g++)
          gi[g] = __builtin_amdgcn_mfma_f32_16x16x32_bf16(wi_f[g][kc], x3[kc], gi[g], 0, 0, 0);
        #pragma unroll
        for (int g = 0; g < 3; g++)
          gh[g] = __builtin_amdgcn_mfma_f32_16x16x32_bf16(wh_f[g][kc], pv[kc], gh[g], 0, 0, 0);
      }
      float4 hp4 = *(const float4*)(prevp + (size_t)(nb0 + n16) * 64 + wv * 16 + q * 4);
      const float hp[4] = {hp4.x, hp4.y, hp4.z, hp4.w};
      unsigned short gB[4];
      #pragma unroll
      for (int r = 0; r < 4; r++){
        const float rv = sigm(gi[0][r] + gh[0][r]);
        const float zv = sigm(gi[1][r] + gh[1][r]);
        const float nv = tanh_(gi[2][r] + rv * gh[2][r]);
        gB[r] = f2b((1.f - zv) * nv + zv * hp[r]);
      }
      *(uint2*)(out_hl + (size_t)(nb0 + n16) * 64 + wv * 16 + q * 4) =
          make_uint2((unsigned)gB[0] | ((unsigned)gB[1] << 16),
                     (unsigned)gB[2] | ((unsigned)gB[3] << 16));
    }
  } else {
    // MODE 1: o=1 logits
    if (wv == 0){
      bf16x8 ws_f[2], wn_f[2];
      #pragma unroll
      for (int kc = 0; kc < 2; kc++){
        U16x8 a, b_;
        a.v = make_uint4(0u,0u,0u,0u); b_.v = make_uint4(0u,0u,0u,0u);
        if (n16 == 0){
          a.b  = load8_bf16(Ws + kc * 32 + q * 8);
          b_.b = load8_bf16(Wn + kc * 32 + q * 8);
        }
        ws_f[kc] = a.b; wn_f[kc] = b_.b;
      }
      f32x4 e = {0.f, 0.f, 0.f, 0.f};
      #pragma unroll
      for (int kc = 0; kc < 2; kc++){
        e = __builtin_amdgcn_mfma_f32_16x16x32_bf16(ws_f[kc], sH[kc], e, 0, 0, 0);
        e = __builtin_amdgcn_mfma_f32_16x16x32_bf16(wn_f[kc], kH[kc], e, 0, 0, 0);
      }
      if (q == 0) out_f32[nb0 + n16] = e[0] + bs[0];
    }
  }
}

// ---------------------------------------------------------------------------
extern "C" void kernel_launch(void* const* d_in, const int* in_sizes, int n_in,
                              void* d_out, int out_size, void* d_ws, size_t ws_size,
                              hipStream_t stream)
{
  (void)in_sizes; (void)n_in; (void)out_size; (void)ws_size;
  const float* x    = (const float*)d_in[0];
  const int*   nbr  = (const int*)d_in[1];
  const float* prev = (const float*)d_in[2];
  auto W = [&](int i){ return (const float*)d_in[i]; };

  unsigned short* tabA = (unsigned short*)d_ws;            // [N][64] u16, 6.4 MB
  unsigned short* tabB = tabA + (size_t)N_NODES * 64;      // second table

  // layer 1 (d=11): x -> tabA (=h1)
  l1_kernel<<<N_NODES / 16, 256, 0, stream>>>(
      x, nbr, W(3), W(4), W(5), W(6), W(7), W(8), W(9), tabA);
  // layer 2: tabA -> tabB (=h2)
  sage64_kernel<0><<<N_NODES / 16, 256, 0, stream>>>(
      tabA, nbr, W(10), W(11), W(12), W(13), W(14), W(15), W(16),
      nullptr, nullptr, nullptr, nullptr, nullptr,
      tabB, nullptr);
  // layer 3 + fused GRU: tabB (+prev) -> tabA (= GRU output h)
  sage64_kernel<2><<<N_NODES / 16, 256, 0, stream>>>(
      tabB, nbr, W(17), W(18), W(19), W(20), W(21), W(22), W(23),
      W(31), W(32), W(33), W(34), prev,
      tabA, nullptr);
  // layer 4 (o=1): tabA -> d_out (fp32 logits)
  sage64_kernel<1><<<N_NODES / 16, 256, 0, stream>>>(
      tabA, nbr, W(24), W(25), W(26), W(27), W(28), W(29), W(30),
      nullptr, nullptr, nullptr, nullptr, nullptr,
      nullptr, (float*)d_out);
}

// Round 14
// 477.323 us; speedup vs baseline: 1.1091x; 1.0078x over previous
//
#include <hip/hip_runtime.h>

#define N_NODES 50000

typedef __bf16 bf16x8 __attribute__((ext_vector_type(8)));
typedef float f32x4 __attribute__((ext_vector_type(4)));

union U16x8 { uint4 v; unsigned short u[8]; bf16x8 b; };

__device__ __forceinline__ float b2f(unsigned short h){
  unsigned int u = ((unsigned int)h) << 16;
  return __builtin_bit_cast(float, u);
}
__device__ __forceinline__ unsigned short f2b(float x){
  unsigned int u = __builtin_bit_cast(unsigned int, x);
  u = u + 0x7FFFu + ((u >> 16) & 1u);
  return (unsigned short)(u >> 16);
}
// raw-hardware sigmoid/tanh: v_exp_f32 + v_rcp_f32, no division refinement.
__device__ __forceinline__ float sigm(float x){
  const float e = __builtin_amdgcn_exp2f(x * -1.4426950408889634f);
  return __builtin_amdgcn_rcpf(1.0f + e);
}
__device__ __forceinline__ float tanh_(float x){
  const float e = __builtin_amdgcn_exp2f(x * 2.8853900817779268f);
  return fmaf(-2.0f, __builtin_amdgcn_rcpf(1.0f + e), 1.0f);
}

// 8 consecutive f32 -> bf16x8 (RNE), hi only
__device__ __forceinline__ bf16x8 load8_bf16(const float* p){
  float4 a = *(const float4*)p; float4 c = *(const float4*)(p + 4);
  U16x8 r;
  r.u[0]=f2b(a.x); r.u[1]=f2b(a.y); r.u[2]=f2b(a.z); r.u[3]=f2b(a.w);
  r.u[4]=f2b(c.x); r.u[5]=f2b(c.y); r.u[6]=f2b(c.z); r.u[7]=f2b(c.w);
  return r.b;
}

// ---------------------------------------------------------------------------
// Activation tables (all inter-layer tensors): u16[node][64], bf16 hi of fp32.
//
// NOTE (r13 post-mortem): full 16x unroll of the step loop caused a
// timing-dependent replay divergence (post-timing tripwire) with ZERO perf
// gain (481.6 vs 481.1 us) — the kernel is latency/occupancy-bound, not
// instruction-bound. Keep the rolled loop; do not unroll across barriers.
// Cross-session clock note: identical code measured 117.6 us (r6) and
// 149.3 us (r12) with uniformly scaled counters — session clock state.
// ---------------------------------------------------------------------------

// ---------------------------------------------------------------------------
// Layer 1 (d=11) via MFMA, bf16 hi-only, single barrier per step. (~20 us)
// ---------------------------------------------------------------------------
__global__ __launch_bounds__(256) void l1_kernel(
    const float* __restrict__ x, const int* __restrict__ nbr,
    const float* __restrict__ Wih, const float* __restrict__ Whh,
    const float* __restrict__ bih, const float* __restrict__ bhh,
    const float* __restrict__ Ws,  const float* __restrict__ bs,
    const float* __restrict__ Wn,  unsigned short* __restrict__ out_hl)
{
  __shared__ unsigned short mbuf[16][16][24];  // [t][node][k] 12.3 KB
  __shared__ unsigned short hbuf[2][16][24];   // [buf][node][unit] 1.5 KB

  const int tid  = threadIdx.x;
  const int wave = tid >> 6, lane = tid & 63;
  const int n16  = lane & 15, q = lane >> 4;
  const int nb0  = blockIdx.x * 16;

  { unsigned int* p = (unsigned int*)hbuf;
    for (int i = tid; i < 384; i += 256) p[i] = 0u; }

  {
    const int nd = tid >> 4, t = tid & 15;
    const int gn = nbr[(nb0 + nd) * 16 + t];
    const float* row = x + (long)gn * 11;
    float v[16];
    #pragma unroll
    for (int j = 0; j < 11; j++) v[j] = row[j];
    #pragma unroll
    for (int j = 11; j < 16; j++) v[j] = 0.f;
    U16x8 A, B;
    #pragma unroll
    for (int j = 0; j < 8; j++){ A.u[j] = f2b(v[j]); B.u[j] = f2b(v[8 + j]); }
    *(uint4*)&mbuf[t][nd][0] = A.v;
    *(uint4*)&mbuf[t][nd][8] = B.v;
  }

  bf16x8 wf[4];
  float bg4[4];
  #pragma unroll
  for (int g = 0; g < 4; g++){
    const int u = n16;
    const float* src = (q < 2) ? (Wih + (g * 11 + u) * 11)
                               : (Whh + (g * 11 + u) * 11);
    const int kb = (q & 1) * 8;
    U16x8 a;
    #pragma unroll
    for (int j = 0; j < 8; j++){
      const int k = kb + j;
      float v = (u < 11 && k < 11) ? src[k] : 0.f;
      a.u[j] = f2b(v);
    }
    wf[g] = a.b;
    bg4[g] = (n16 < 11) ? (bih[g * 11 + n16] + bhh[g * 11 + n16]) : 0.f;
  }

  float c_ = 0.f;   // cell state for (node q*4+wave, unit n16)
  __syncthreads();

  for (int t = 0; t < 16; t++){
    const int db = t & 1, nb = db ^ 1;

    const unsigned short* ph = (q < 2) ? &mbuf[t][n16][q * 8]
                                       : &hbuf[db][n16][(q - 2) * 8];
    U16x8 ah; ah.v = *(const uint4*)ph;

    f32x4 acc[4];
    #pragma unroll
    for (int g = 0; g < 4; g++){
      f32x4 av = {bg4[g], bg4[g], bg4[g], bg4[g]};
      acc[g] = __builtin_amdgcn_mfma_f32_16x16x32_bf16(ah.b, wf[g], av, 0, 0, 0);
    }

    {
      const float iv = sigm(acc[0][wave]);
      const float fv = sigm(acc[1][wave]);
      const float gg = tanh_(acc[2][wave]);
      const float ov = sigm(acc[3][wave]);
      c_ = fv * c_ + iv * gg;
      hbuf[nb][q * 4 + wave][n16] = f2b(ov * tanh_(c_));
    }
    __syncthreads();
  }

  // ---- epilogue ----
  U16x8 ea;
  if (q < 2){
    const float* row = x + (long)(nb0 + n16) * 11;
    U16x8 H;
    #pragma unroll
    for (int j = 0; j < 8; j++){
      const int k = q * 8 + j;
      H.u[j] = f2b((k < 11) ? row[k] : 0.f);
    }
    ea = H;
  } else {
    ea.v = *(const uint4*)&hbuf[0][n16][(q - 2) * 8];
  }

  bf16x8 ewf;
  {
    const int uo = wave * 16 + n16;
    const float* src = (q < 2) ? (Ws + uo * 11) : (Wn + uo * 11);
    const int kb = (q & 1) * 8;
    U16x8 a;
    #pragma unroll
    for (int j = 0; j < 8; j++){
      const int k = kb + j;
      a.u[j] = f2b((k < 11) ? src[k] : 0.f);
    }
    ewf = a.b;
  }

  {
    const int uo = wave * 16 + n16;
    const float bsv = bs[uo];
    f32x4 e = {bsv, bsv, bsv, bsv};
    e = __builtin_amdgcn_mfma_f32_16x16x32_bf16(ea.b, ewf, e, 0, 0, 0);
    #pragma unroll
    for (int r = 0; r < 4; r++)
      out_hl[(size_t)(nb0 + q * 4 + r) * 64 + uo] = f2b(fmaxf(e[r], 0.f));
  }
}

// ---------------------------------------------------------------------------
// Layers 2/3/4: transposed MFMA (A=weights rows=units, B=[m;h] cols=nodes),
// bf16 hi-only activations, ALL 16 m-rows burst-prefetched upfront (r6-proven
// body). Swizzled LDS slots. ROLLED step loop (see r13 note above).
// MODE is a TEMPLATE param (r10: shared-function regalloc pollution taxed
// all modes). __launch_bounds__(256,3) ONLY: (256,4)->VGPR 64 spill 137 MB;
// (256,5)->VGPR 48 spill 293 MB.
// MODE 0: out_hl = relu(hself@WsT + bs + hK@WnT)          (u16 table)
// MODE 1: out_f32[n] = hself@WsT + bs + hK@WnT (o=1)
// MODE 2: mode-0 compute (=h3, not stored) + fused GRUCell -> out_hl
//         (fusion kills the standalone gru kernel, ~120 us of dark matter)
// ---------------------------------------------------------------------------
template<int MODE>
__global__ __launch_bounds__(256, 3) void sage64_kernel(
    const unsigned short* __restrict__ in_hl, const int* __restrict__ nbr,
    const float* __restrict__ Wih, const float* __restrict__ Whh,
    const float* __restrict__ bih, const float* __restrict__ bhh,
    const float* __restrict__ Ws,  const float* __restrict__ bs,
    const float* __restrict__ Wn,
    const float* __restrict__ gWih, const float* __restrict__ gWhh,
    const float* __restrict__ gbih, const float* __restrict__ gbhh,
    const float* __restrict__ prevp,
    unsigned short* __restrict__ out_hl, float* __restrict__ out_f32)
{
  __shared__ uint4 mbuf[16][16][8];   // [t][node][slot sw (s+nd+t)&7]  32 KB
  __shared__ uint4 hbuf[2][16][8];    // [buf][node][slot sw (s+n)&7]    4 KB

  const int tid = threadIdx.x;
  const int wv = tid >> 6, lane = tid & 63;
  const int n16 = lane & 15, q = lane >> 4;
  const int nb0 = blockIdx.x * 16;

  // burst prefetch: thread (nd, t) loads one 128B neighbor row
  {
    const int nd = tid >> 4, t = tid & 15;
    const int gn = nbr[(nb0 + nd) * 16 + t];
    const uint4* src = (const uint4*)(in_hl + (size_t)gn * 64);
    #pragma unroll
    for (int s = 0; s < 8; s++)
      mbuf[t][nd][(s + nd + t) & 7] = src[s];
  }
  // zero hbuf[0] (initial h)
  { unsigned int* p = (unsigned int*)&hbuf[0][0][0];
    for (int i = tid; i < 512; i += 256) p[i] = 0u; }

  // resident weight A-frags (hi only): gate g, kc; lane row = unit wv*16+n16
  bf16x8 wih_f[4][2], whh_f[4][2];
  #pragma unroll
  for (int g = 0; g < 4; g++){
    const int row = g * 64 + wv * 16 + n16;
    #pragma unroll
    for (int kc = 0; kc < 2; kc++){
      wih_f[g][kc] = load8_bf16(Wih + row * 64 + kc * 32 + q * 8);
      whh_f[g][kc] = load8_bf16(Whh + row * 64 + kc * 32 + q * 8);
    }
  }
  f32x4 bg[4];
  #pragma unroll
  for (int g = 0; g < 4; g++){
    float4 bi = *(const float4*)(bih + g * 64 + wv * 16 + q * 4);
    float4 bh = *(const float4*)(bhh + g * 64 + wv * 16 + q * 4);
    f32x4 s = {bi.x + bh.x, bi.y + bh.y, bi.z + bh.z, bi.w + bh.w};
    bg[g] = s;
  }

  float c4[4] = {0.f, 0.f, 0.f, 0.f};
  __syncthreads();

  for (int t = 0; t < 16; t++){
    const int db = t & 1, nbf = db ^ 1;

    bf16x8 mh[2], hh[2];
    #pragma unroll
    for (int kc = 0; kc < 2; kc++){
      U16x8 a; a.v = mbuf[t][n16][(kc * 4 + q + n16 + t) & 7];  mh[kc] = a.b;
      U16x8 c_; c_.v = hbuf[db][n16][(kc * 4 + q + n16) & 7];   hh[kc] = c_.b;
    }

    f32x4 acc[4];
    #pragma unroll
    for (int g = 0; g < 4; g++) acc[g] = bg[g];
    #pragma unroll
    for (int kc = 0; kc < 2; kc++){
      #pragma unroll
      for (int g = 0; g < 4; g++)
        acc[g] = __builtin_amdgcn_mfma_f32_16x16x32_bf16(wih_f[g][kc], mh[kc], acc[g], 0, 0, 0);
      #pragma unroll
      for (int g = 0; g < 4; g++)
        acc[g] = __builtin_amdgcn_mfma_f32_16x16x32_bf16(whh_f[g][kc], hh[kc], acc[g], 0, 0, 0);
    }

    unsigned short hB[4];
    #pragma unroll
    for (int r = 0; r < 4; r++){
      const float iv = sigm(acc[0][r]);
      const float fv = sigm(acc[1][r]);
      const float gg = tanh_(acc[2][r]);
      const float ov = sigm(acc[3][r]);
      c4[r] = fv * c4[r] + iv * gg;
      hB[r] = f2b(ov * tanh_(c4[r]));
    }
    {
      const int idx = wv * 4 + q;            // uint2 index within node row
      const int slot = idx >> 1, half = idx & 1;
      ((uint2*)&hbuf[nbf][n16][(slot + n16) & 7])[half] =
          make_uint2((unsigned)hB[0] | ((unsigned)hB[1] << 16),
                     (unsigned)hB[2] | ((unsigned)hB[3] << 16));
    }
    __syncthreads();
  }

  // ---- epilogue: B = hself (global, hi) and hK (hbuf[0]) ----
  bf16x8 sH[2], kH[2];
  #pragma unroll
  for (int kc = 0; kc < 2; kc++){
    U16x8 a; a.v = *(const uint4*)(in_hl + (size_t)(nb0 + n16) * 64 + kc * 32 + q * 8);
    sH[kc] = a.b;
    U16x8 c_; c_.v = hbuf[0][n16][(kc * 4 + q + n16) & 7]; kH[kc] = c_.b;
  }

  if constexpr (MODE != 1){
    bf16x8 ws_f[2], wn_f[2];
    #pragma unroll
    for (int kc = 0; kc < 2; kc++){
      ws_f[kc] = load8_bf16(Ws + (wv * 16 + n16) * 64 + kc * 32 + q * 8);
      wn_f[kc] = load8_bf16(Wn + (wv * 16 + n16) * 64 + kc * 32 + q * 8);
    }
    float4 bsv = *(const float4*)(bs + wv * 16 + q * 4);
    f32x4 e = {bsv.x, bsv.y, bsv.z, bsv.w};
    #pragma unroll
    for (int kc = 0; kc < 2; kc++){
      e = __builtin_amdgcn_mfma_f32_16x16x32_bf16(ws_f[kc], sH[kc], e, 0, 0, 0);
      e = __builtin_amdgcn_mfma_f32_16x16x32_bf16(wn_f[kc], kH[kc], e, 0, 0, 0);
    }
    unsigned short oB[4];
    #pragma unroll
    for (int r = 0; r < 4; r++) oB[r] = f2b(fmaxf(e[r], 0.f));
    const uint2 packed = make_uint2((unsigned)oB[0] | ((unsigned)oB[1] << 16),
                                    (unsigned)oB[2] | ((unsigned)oB[3] << 16));

    if constexpr (MODE == 0){
      *(uint2*)(out_hl + (size_t)(nb0 + n16) * 64 + wv * 16 + q * 4) = packed;
    } else {
      // ---- MODE 2: fused GRUCell. Stage h3 into hbuf[1] (B-frag layout) ----
      {
        const int idx = wv * 4 + q;
        const int slot = idx >> 1, half = idx & 1;
        ((uint2*)&hbuf[1][n16][(slot + n16) & 7])[half] = packed;
      }
      __syncthreads();

      bf16x8 x3[2], pv[2];
      #pragma unroll
      for (int kc = 0; kc < 2; kc++){
        U16x8 a; a.v = hbuf[1][n16][(kc * 4 + q + n16) & 7]; x3[kc] = a.b;
        pv[kc] = load8_bf16(prevp + (size_t)(nb0 + n16) * 64 + kc * 32 + q * 8);
      }
      bf16x8 wi_f[3][2], wh_f[3][2];
      #pragma unroll
      for (int g = 0; g < 3; g++){
        const int row = g * 64 + wv * 16 + n16;
        #pragma unroll
        for (int kc = 0; kc < 2; kc++){
          wi_f[g][kc] = load8_bf16(gWih + row * 64 + kc * 32 + q * 8);
          wh_f[g][kc] = load8_bf16(gWhh + row * 64 + kc * 32 + q * 8);
        }
      }
      f32x4 gi[3], gh[3];
      #pragma unroll
      for (int g = 0; g < 3; g++){
        float4 bi = *(const float4*)(gbih + g * 64 + wv * 16 + q * 4);
        float4 bh = *(const float4*)(gbhh + g * 64 + wv * 16 + q * 4);
        f32x4 vi = {bi.x, bi.y, bi.z, bi.w}; gi[g] = vi;
        f32x4 vh = {bh.x, bh.y, bh.z, bh.w}; gh[g] = vh;
      }
      #pragma unroll
      for (int kc = 0; kc < 2; kc++){
        #pragma unroll
        for (int g = 0; g < 3; g++)
          gi[g] = __builtin_amdgcn_mfma_f32_16x16x32_bf16(wi_f[g][kc], x3[kc], gi[g], 0, 0, 0);
        #pragma unroll
        for (int g = 0; g < 3; g++)
          gh[g] = __builtin_amdgcn_mfma_f32_16x16x32_bf16(wh_f[g][kc], pv[kc], gh[g], 0, 0, 0);
      }
      float4 hp4 = *(const float4*)(prevp + (size_t)(nb0 + n16) * 64 + wv * 16 + q * 4);
      const float hp[4] = {hp4.x, hp4.y, hp4.z, hp4.w};
      unsigned short gB[4];
      #pragma unroll
      for (int r = 0; r < 4; r++){
        const float rv = sigm(gi[0][r] + gh[0][r]);
        const float zv = sigm(gi[1][r] + gh[1][r]);
        const float nv = tanh_(gi[2][r] + rv * gh[2][r]);
        gB[r] = f2b((1.f - zv) * nv + zv * hp[r]);
      }
      *(uint2*)(out_hl + (size_t)(nb0 + n16) * 64 + wv * 16 + q * 4) =
          make_uint2((unsigned)gB[0] | ((unsigned)gB[1] << 16),
                     (unsigned)gB[2] | ((unsigned)gB[3] << 16));
    }
  } else {
    // MODE 1: o=1 logits
    if (wv == 0){
      bf16x8 ws_f[2], wn_f[2];
      #pragma unroll
      for (int kc = 0; kc < 2; kc++){
        U16x8 a, b_;
        a.v = make_uint4(0u,0u,0u,0u); b_.v = make_uint4(0u,0u,0u,0u);
        if (n16 == 0){
          a.b  = load8_bf16(Ws + kc * 32 + q * 8);
          b_.b = load8_bf16(Wn + kc * 32 + q * 8);
        }
        ws_f[kc] = a.b; wn_f[kc] = b_.b;
      }
      f32x4 e = {0.f, 0.f, 0.f, 0.f};
      #pragma unroll
      for (int kc = 0; kc < 2; kc++){
        e = __builtin_amdgcn_mfma_f32_16x16x32_bf16(ws_f[kc], sH[kc], e, 0, 0, 0);
        e = __builtin_amdgcn_mfma_f32_16x16x32_bf16(wn_f[kc], kH[kc], e, 0, 0, 0);
      }
      if (q == 0) out_f32[nb0 + n16] = e[0] + bs[0];
    }
  }
}

// ---------------------------------------------------------------------------
extern "C" void kernel_launch(void* const* d_in, const int* in_sizes, int n_in,
                              void* d_out, int out_size, void* d_ws, size_t ws_size,
                              hipStream_t stream)
{
  (void)in_sizes; (void)n_in; (void)out_size; (void)ws_size;
  const float* x    = (const float*)d_in[0];
  const int*   nbr  = (const int*)d_in[1];
  const float* prev = (const float*)d_in[2];
  auto W = [&](int i){ return (const float*)d_in[i]; };

  unsigned short* tabA = (unsigned short*)d_ws;            // [N][64] u16, 6.4 MB
  unsigned short* tabB = tabA + (size_t)N_NODES * 64;      // second table

  // layer 1 (d=11): x -> tabA (=h1)
  l1_kernel<<<N_NODES / 16, 256, 0, stream>>>(
      x, nbr, W(3), W(4), W(5), W(6), W(7), W(8), W(9), tabA);
  // layer 2: tabA -> tabB (=h2)
  sage64_kernel<0><<<N_NODES / 16, 256, 0, stream>>>(
      tabA, nbr, W(10), W(11), W(12), W(13), W(14), W(15), W(16),
      nullptr, nullptr, nullptr, nullptr, nullptr,
      tabB, nullptr);
  // layer 3 + fused GRU: tabB (+prev) -> tabA (= GRU output h)
  sage64_kernel<2><<<N_NODES / 16, 256, 0, stream>>>(
      tabB, nbr, W(17), W(18), W(19), W(20), W(21), W(22), W(23),
      W(31), W(32), W(33), W(34), prev,
      tabA, nullptr);
  // layer 4 (o=1): tabA -> d_out (fp32 logits)
  sage64_kernel<1><<<N_NODES / 16, 256, 0, stream>>>(
      tabA, nbr, W(24), W(25), W(26), W(27), W(28), W(29), W(30),
      nullptr, nullptr, nullptr, nullptr, nullptr,
      nullptr, (float*)d_out);
}